// Round 8
// baseline (378.468 us; speedup 1.0000x reference)
//
#include <hip/hip_runtime.h>

// ---------------------------------------------------------------------------
// Geometry: B=16, H=W=1024, kh0=512 kw0=256 -> ph=2, pw=4, L=8; 128 patches.
// Pass 1 (k_err): ROUND-5 version (proven): 4096-px chunks, 4 f32x4 slots.
//   blocks/patch: s0=32,s1=8,s2=2,s3=1 -> bases {0,4096,5120,5376}, 5504 tot.
//   Partials SoA chunk-major: id = base_i + chunk*128 + patch (A,N,Q planes).
// Pass 2 (k_finalize): ROUND-5 version; EXPLICIT nch {32,8,2,1}.
// Pass 3 (k_write): REDESIGNED block-uniform-m. Block=(patch,8-row strip);
//   m=mask[patch] uniform per block -> scalar pointer select, no wave
//   divergence on scale. Thread k<31: cols 8k+3..8k+10, two aligned f32x4 NT
//   stores (d_out+1 => col≡3 mod 4 aligned); reads = 3 aligned f32x4 per img
//   covering floats cc-3..cc+8 (in-row for all m,k: cc>=3, cc+8<=kw-1).
//   Thread k==31: leftover cols {0,1,2,251..255} scalar. Pad rows/cols: 0.001.
// ---------------------------------------------------------------------------

typedef float f32x4 __attribute__((ext_vector_type(4)));

__global__ __launch_bounds__(256) void k_err(
    const float* __restrict__ pre0, const float* __restrict__ gt0,
    const float* __restrict__ pre1, const float* __restrict__ gt1,
    const float* __restrict__ pre2, const float* __restrict__ gt2,
    const float* __restrict__ pre3, const float* __restrict__ gt3,
    float* __restrict__ pA, float* __restrict__ pN, float* __restrict__ pQ)
{
    const int bid = blockIdx.x;
    int scale, patch, chunk, oidx;
    const float* __restrict__ pre;
    const float* __restrict__ gt;
    if (bid < 4096)      { scale = 0; patch = bid >> 5; chunk = bid & 31;
                           oidx = chunk * 128 + patch;          pre = pre0; gt = gt0; }
    else if (bid < 5120) { scale = 1; int r = bid - 4096; patch = r >> 3; chunk = r & 7;
                           oidx = 4096 + chunk * 128 + patch;   pre = pre1; gt = gt1; }
    else if (bid < 5376) { scale = 2; int r = bid - 5120; patch = r >> 1; chunk = r & 1;
                           oidx = 5120 + chunk * 128 + patch;   pre = pre2; gt = gt2; }
    else                 { scale = 3; patch = bid - 5376; chunk = 0;
                           oidx = 5376 + patch;                 pre = pre3; gt = gt3; }

    const int b  = patch >> 3;
    const int l  = patch & 7;
    const int pi = l >> 2, pj = l & 3;
    const int kwshift = 8 - scale;            // kw = 256>>scale
    const int kw   = 1 << kwshift;
    const int kh   = 512 >> scale;
    const int wdim = 1024 >> scale;
    const int patch_px = 131072 >> (2 * scale);
    const int imgbase  = b * wdim * wdim;
    const int base_row = pi * kh;
    const int base_col = pj * kw;

    const int t = threadIdx.x;
    float sumabs = 0.f, npos = 0.f, sq = 0.f;

#pragma unroll
    for (int s = 0; s < 4; ++s) {
        const int slot = t + s * 256;                 // 0..1023 float4 slots
        const int px   = chunk * 4096 + slot * 4;     // pixel index within patch
        if (px < patch_px) {                          // wave-uniform (only s3 trims)
            const int row  = px >> kwshift;
            const int col  = px & (kw - 1);
            const int idx  = imgbase + (base_row + row) * wdim + base_col + col;
            const f32x4 p = *reinterpret_cast<const f32x4*>(pre + idx);
            const f32x4 g = *reinterpret_cast<const f32x4*>(gt + idx);
#pragma unroll
            for (int k = 0; k < 4; ++k) {
                const float gs = g[k] * 200.0f;       // gts = gt * WEIGHT
                const float d  = gs - p[k];
                sq += d * d;                          // loss term: all pixels
                if (g[k] > 0.0f) { sumabs += fabsf(d); npos += 1.0f; }
            }
        }
    }

    for (int off = 32; off > 0; off >>= 1) {
        sumabs += __shfl_down(sumabs, off);
        npos   += __shfl_down(npos,   off);
        sq     += __shfl_down(sq,     off);
    }
    __shared__ float wA[4], wN[4], wQ[4];
    const int w = t >> 6;
    if ((t & 63) == 0) { wA[w] = sumabs; wN[w] = npos; wQ[w] = sq; }
    __syncthreads();
    if (t == 0) {
        pA[oidx] = (wA[0] + wA[1]) + (wA[2] + wA[3]);
        pN[oidx] = (wN[0] + wN[1]) + (wN[2] + wN[3]);
        pQ[oidx] = (wQ[0] + wQ[1]) + (wQ[2] + wQ[3]);
    }
}

__global__ __launch_bounds__(256) void k_finalize(
    const float* __restrict__ pA, const float* __restrict__ pN, const float* __restrict__ pQ,
    int* __restrict__ mask, float* __restrict__ loss_out)
{
    const int t = threadIdx.x;
    __shared__ float A[512], N[512], Q[512];   // [i*128 + p]
    __shared__ float qsel[128];
    __shared__ int   msel[128];

    const int p  = t & 127;
    const int i0 = (t < 128) ? 0 : 1;
#pragma unroll
    for (int k = 0; k < 2; ++k) {
        const int i    = i0 + 2 * k;
        const int base = (i == 0) ? 0 : (i == 1) ? 4096 : (i == 2) ? 5120 : 5376;
        const int nch  = (i == 0) ? 32 : (i == 1) ? 8 : (i == 2) ? 2 : 1;   // EXPLICIT
        float a = 0.f, n = 0.f, q = 0.f;
#pragma unroll 4
        for (int c = 0; c < nch; ++c) {
            const int id = base + c * 128 + p;     // coalesced
            a += pA[id]; n += pN[id]; q += pQ[id];
        }
        A[i * 128 + p] = a; N[i * 128 + p] = n; Q[i * 128 + p] = q;
    }
    __syncthreads();

    if (t < 128) {
        const float e0 = A[t]       / (N[t]       + 0.1f);
        const float e1 = A[128 + t] / (N[128 + t] + 0.1f);
        const float e2 = A[256 + t] / (N[256 + t] + 0.1f);
        const float e3 = A[384 + t] / (N[384 + t] + 0.1f);
        int best = 0; float bv = e0;
        if (e1 < bv) { bv = e1; best = 1; }
        if (e2 < bv) { bv = e2; best = 2; }
        if (e3 < bv) { bv = e3; best = 3; }
        mask[t] = best;
        msel[t] = best;
        qsel[t] = Q[best * 128 + t];
    }
    __syncthreads();

    float loss = 0.f;
    const float wgt[4] = {0.5f, 0.25f, 0.125f, 0.0625f};
#pragma unroll
    for (int i = 0; i < 4; ++i) {
        if (t < 128) { A[t] = (msel[t] == i) ? qsel[t] : 0.f;
                       N[t] = (msel[t] == i) ? 1.f     : 0.f; }
        __syncthreads();
        for (int off = 64; off > 0; off >>= 1) {
            if (t < off) { A[t] += A[t + off]; N[t] += N[t + off]; }
            __syncthreads();
        }
        if (t == 0) {
            const float px = (float)(131072 >> (2 * i));   // kh_i*kw_i
            loss += wgt[i] * (A[0] / (N[0] * px + 0.01f));
        }
        __syncthreads();
    }
    if (t == 0) loss_out[0] = loss;
}

// Block-uniform-m output pass. Block = (patch 0..127, strip 0..63).
// Strip = 8 out-rows; thread (t>>5) picks row, k=t&31 picks col group.
__global__ __launch_bounds__(256) void k_write(
    const float* __restrict__ pre0, const float* __restrict__ gt0,
    const float* __restrict__ pre1, const float* __restrict__ gt1,
    const float* __restrict__ pre2, const float* __restrict__ gt2,
    const float* __restrict__ pre3, const float* __restrict__ gt3,
    const int* __restrict__ mask, float* __restrict__ out)
{
    const int NPIX = 16 * 1024 * 1024;
    const int bid   = blockIdx.x;
    const int patch = bid >> 6;          // 0..127
    const int strip = bid & 63;          // 0..63
    const int b  = patch >> 3;
    const int pi = (patch >> 2) & 1;
    const int pj = patch & 3;
    const int m  = mask[patch];          // block-uniform -> scalar
    const int kh = 512 >> m, kw = 256 >> m;
    const int wdim  = 1024 >> m;
    const int pad_h = (512 - kh) >> 1;
    const int pad_w = (256 - kw) >> 1;
    const float* __restrict__ pre = (m == 0) ? pre0 : (m == 1) ? pre1 : (m == 2) ? pre2 : pre3;
    const float* __restrict__ gt  = (m == 0) ? gt0  : (m == 1) ? gt1  : (m == 2) ? gt2  : gt3;

    const int t   = threadIdx.x;
    const int row = strip * 8 + (t >> 5);          // 0..511 within patch
    const int k   = t & 31;

    float* __restrict__ out_img = out + 1;
    float* __restrict__ lab_img = out + 1 + NPIX;
    const int obase = (b << 20) | ((pi * 512 + row) << 10) | (pj << 8);  // +col

    const int  rr     = row - pad_h;
    const bool row_in = (unsigned)rr < (unsigned)kh;
    const int  ibase  = b * wdim * wdim + (pi * kh + rr) * wdim + pj * kw;  // +cc (valid iff row_in)

    if (k < 31) {
        const int col0 = 8 * k + 3;
        const int cc0  = col0 - pad_w;
        f32x4 oa, ob, la, lb;
        if (row_in && cc0 >= 0 && cc0 + 7 < kw) {
            // all-interior: 3 aligned f32x4 per image cover floats cc0-3..cc0+8
            const int a0 = ibase + cc0 - 3;        // ≡0 mod 4 -> 16B aligned
            const f32x4 pa = *reinterpret_cast<const f32x4*>(pre + a0);
            const f32x4 pb = *reinterpret_cast<const f32x4*>(pre + a0 + 4);
            const f32x4 pc = *reinterpret_cast<const f32x4*>(pre + a0 + 8);
            const f32x4 ga = *reinterpret_cast<const f32x4*>(gt + a0);
            const f32x4 gb = *reinterpret_cast<const f32x4*>(gt + a0 + 4);
            const f32x4 gc = *reinterpret_cast<const f32x4*>(gt + a0 + 8);
            oa = (f32x4){pa[3], pb[0], pb[1], pb[2]} * 0.005f;
            ob = (f32x4){pb[3], pc[0], pc[1], pc[2]} * 0.005f;
            la = (f32x4){ga[3], gb[0], gb[1], gb[2]};
            lb = (f32x4){gb[3], gc[0], gc[1], gc[2]};
        } else {
            // pad rows, or groups straddling the pad/interior column boundary
#pragma unroll
            for (int p = 0; p < 8; ++p) {
                const int cc = cc0 + p;
                float ov = 0.001f, lv = 0.001f;    // 0.2 / WEIGHT
                if (row_in && (unsigned)cc < (unsigned)kw) {
                    ov = pre[ibase + cc] * 0.005f;
                    lv = gt[ibase + cc];
                }
                if (p < 4) { oa[p] = ov; la[p] = lv; }
                else       { ob[p - 4] = ov; lb[p - 4] = lv; }
            }
        }
        __builtin_nontemporal_store(oa, reinterpret_cast<f32x4*>(out_img + obase + col0));
        __builtin_nontemporal_store(ob, reinterpret_cast<f32x4*>(out_img + obase + col0 + 4));
        __builtin_nontemporal_store(la, reinterpret_cast<f32x4*>(lab_img + obase + col0));
        __builtin_nontemporal_store(lb, reinterpret_cast<f32x4*>(lab_img + obase + col0 + 4));
    } else {
        // leftover cols of this row: {0,1,2, 251..255}
        const int cols[8] = {0, 1, 2, 251, 252, 253, 254, 255};
#pragma unroll
        for (int p = 0; p < 8; ++p) {
            const int col = cols[p];
            const int cc  = col - pad_w;
            float ov = 0.001f, lv = 0.001f;
            if (row_in && (unsigned)cc < (unsigned)kw) {
                ov = pre[ibase + cc] * 0.005f;
                lv = gt[ibase + cc];
            }
            __builtin_nontemporal_store(ov, out_img + obase + col);
            __builtin_nontemporal_store(lv, lab_img + obase + col);
        }
    }
}

extern "C" void kernel_launch(void* const* d_in, const int* in_sizes, int n_in,
                              void* d_out, int out_size, void* d_ws, size_t ws_size,
                              hipStream_t stream) {
    // setup_inputs() dict order is INTERLEAVED: pre0, gt0, pre1, gt1, ...
    const float* pre0 = (const float*)d_in[0];
    const float* gt0  = (const float*)d_in[1];
    const float* pre1 = (const float*)d_in[2];
    const float* gt1  = (const float*)d_in[3];
    const float* pre2 = (const float*)d_in[4];
    const float* gt2  = (const float*)d_in[5];
    const float* pre3 = (const float*)d_in[6];
    const float* gt3  = (const float*)d_in[7];

    float* out = (float*)d_out;             // [0]=loss, [1..]=out_img, then lab_img
    float* pA  = (float*)d_ws;              // 5504 each, SoA planes
    float* pN  = pA + 5504;
    float* pQ  = pA + 11008;
    int*   mask = (int*)(pA + 16512);       // 128 ints

    k_err<<<5504, 256, 0, stream>>>(pre0, gt0, pre1, gt1, pre2, gt2, pre3, gt3, pA, pN, pQ);
    k_finalize<<<1, 256, 0, stream>>>(pA, pN, pQ, mask, out);
    k_write<<<8192, 256, 0, stream>>>(pre0, gt0, pre1, gt1, pre2, gt2, pre3, gt3, mask, out);
}

// Round 9
// 310.639 us; speedup vs baseline: 1.2184x; 1.2184x over previous
//
#include <hip/hip_runtime.h>

// ---------------------------------------------------------------------------
// Geometry: B=16, H=W=1024, kh0=512 kw0=256 -> ph=2, pw=4, L=8; 128 patches.
// Pass 1 (k_err): ROUND-5 version (proven): 4096-px chunks, 4 f32x4 slots.
//   blocks/patch: s0=32,s1=8,s2=2,s3=1 -> bases {0,4096,5120,5376}, 5504 tot.
//   Partials SoA chunk-major: id = base_i + chunk*128 + patch (A,N,Q planes).
// Pass 2 (k_finalize): ROUND-5 version; EXPLICIT nch {32,8,2,1}.
// Pass 3 (k_write): wave = one patch row. Lanes 0..62: cols 4l+3..4l+6 ->
//   lane-contiguous f32x4 NT stores (1008B/instr, no gaps — round-8 lesson:
//   strided 16B NT stores inflate WRITE_SIZE 1.75x). Lane 63: cols {0,1,2,255}.
//   m = mask[patch] block-uniform -> scalar pointer select. Interior reads =
//   two ALIGNED f32x4 (a0=ibase+cc0-3 ≡ 0 mod 4) + shuffle; reads are L3-warm
//   (round-8: FETCH 9.5MB). Boundary lanes (<=2/wave) scalar masked path.
// ---------------------------------------------------------------------------

typedef float f32x4 __attribute__((ext_vector_type(4)));

__global__ __launch_bounds__(256) void k_err(
    const float* __restrict__ pre0, const float* __restrict__ gt0,
    const float* __restrict__ pre1, const float* __restrict__ gt1,
    const float* __restrict__ pre2, const float* __restrict__ gt2,
    const float* __restrict__ pre3, const float* __restrict__ gt3,
    float* __restrict__ pA, float* __restrict__ pN, float* __restrict__ pQ)
{
    const int bid = blockIdx.x;
    int scale, patch, chunk, oidx;
    const float* __restrict__ pre;
    const float* __restrict__ gt;
    if (bid < 4096)      { scale = 0; patch = bid >> 5; chunk = bid & 31;
                           oidx = chunk * 128 + patch;          pre = pre0; gt = gt0; }
    else if (bid < 5120) { scale = 1; int r = bid - 4096; patch = r >> 3; chunk = r & 7;
                           oidx = 4096 + chunk * 128 + patch;   pre = pre1; gt = gt1; }
    else if (bid < 5376) { scale = 2; int r = bid - 5120; patch = r >> 1; chunk = r & 1;
                           oidx = 5120 + chunk * 128 + patch;   pre = pre2; gt = gt2; }
    else                 { scale = 3; patch = bid - 5376; chunk = 0;
                           oidx = 5376 + patch;                 pre = pre3; gt = gt3; }

    const int b  = patch >> 3;
    const int l  = patch & 7;
    const int pi = l >> 2, pj = l & 3;
    const int kwshift = 8 - scale;            // kw = 256>>scale
    const int kw   = 1 << kwshift;
    const int kh   = 512 >> scale;
    const int wdim = 1024 >> scale;
    const int patch_px = 131072 >> (2 * scale);
    const int imgbase  = b * wdim * wdim;
    const int base_row = pi * kh;
    const int base_col = pj * kw;

    const int t = threadIdx.x;
    float sumabs = 0.f, npos = 0.f, sq = 0.f;

#pragma unroll
    for (int s = 0; s < 4; ++s) {
        const int slot = t + s * 256;                 // 0..1023 float4 slots
        const int px   = chunk * 4096 + slot * 4;     // pixel index within patch
        if (px < patch_px) {                          // wave-uniform (only s3 trims)
            const int row  = px >> kwshift;
            const int col  = px & (kw - 1);
            const int idx  = imgbase + (base_row + row) * wdim + base_col + col;
            const f32x4 p = *reinterpret_cast<const f32x4*>(pre + idx);
            const f32x4 g = *reinterpret_cast<const f32x4*>(gt + idx);
#pragma unroll
            for (int k = 0; k < 4; ++k) {
                const float gs = g[k] * 200.0f;       // gts = gt * WEIGHT
                const float d  = gs - p[k];
                sq += d * d;                          // loss term: all pixels
                if (g[k] > 0.0f) { sumabs += fabsf(d); npos += 1.0f; }
            }
        }
    }

    for (int off = 32; off > 0; off >>= 1) {
        sumabs += __shfl_down(sumabs, off);
        npos   += __shfl_down(npos,   off);
        sq     += __shfl_down(sq,     off);
    }
    __shared__ float wA[4], wN[4], wQ[4];
    const int w = t >> 6;
    if ((t & 63) == 0) { wA[w] = sumabs; wN[w] = npos; wQ[w] = sq; }
    __syncthreads();
    if (t == 0) {
        pA[oidx] = (wA[0] + wA[1]) + (wA[2] + wA[3]);
        pN[oidx] = (wN[0] + wN[1]) + (wN[2] + wN[3]);
        pQ[oidx] = (wQ[0] + wQ[1]) + (wQ[2] + wQ[3]);
    }
}

__global__ __launch_bounds__(256) void k_finalize(
    const float* __restrict__ pA, const float* __restrict__ pN, const float* __restrict__ pQ,
    int* __restrict__ mask, float* __restrict__ loss_out)
{
    const int t = threadIdx.x;
    __shared__ float A[512], N[512], Q[512];   // [i*128 + p]
    __shared__ float qsel[128];
    __shared__ int   msel[128];

    const int p  = t & 127;
    const int i0 = (t < 128) ? 0 : 1;
#pragma unroll
    for (int k = 0; k < 2; ++k) {
        const int i    = i0 + 2 * k;
        const int base = (i == 0) ? 0 : (i == 1) ? 4096 : (i == 2) ? 5120 : 5376;
        const int nch  = (i == 0) ? 32 : (i == 1) ? 8 : (i == 2) ? 2 : 1;   // EXPLICIT
        float a = 0.f, n = 0.f, q = 0.f;
#pragma unroll 4
        for (int c = 0; c < nch; ++c) {
            const int id = base + c * 128 + p;     // coalesced
            a += pA[id]; n += pN[id]; q += pQ[id];
        }
        A[i * 128 + p] = a; N[i * 128 + p] = n; Q[i * 128 + p] = q;
    }
    __syncthreads();

    if (t < 128) {
        const float e0 = A[t]       / (N[t]       + 0.1f);
        const float e1 = A[128 + t] / (N[128 + t] + 0.1f);
        const float e2 = A[256 + t] / (N[256 + t] + 0.1f);
        const float e3 = A[384 + t] / (N[384 + t] + 0.1f);
        int best = 0; float bv = e0;
        if (e1 < bv) { bv = e1; best = 1; }
        if (e2 < bv) { bv = e2; best = 2; }
        if (e3 < bv) { bv = e3; best = 3; }
        mask[t] = best;
        msel[t] = best;
        qsel[t] = Q[best * 128 + t];
    }
    __syncthreads();

    float loss = 0.f;
    const float wgt[4] = {0.5f, 0.25f, 0.125f, 0.0625f};
#pragma unroll
    for (int i = 0; i < 4; ++i) {
        if (t < 128) { A[t] = (msel[t] == i) ? qsel[t] : 0.f;
                       N[t] = (msel[t] == i) ? 1.f     : 0.f; }
        __syncthreads();
        for (int off = 64; off > 0; off >>= 1) {
            if (t < off) { A[t] += A[t + off]; N[t] += N[t + off]; }
            __syncthreads();
        }
        if (t == 0) {
            const float px = (float)(131072 >> (2 * i));   // kh_i*kw_i
            loss += wgt[i] * (A[0] / (N[0] * px + 0.01f));
        }
        __syncthreads();
    }
    if (t == 0) loss_out[0] = loss;
}

// Wave = one patch row; block = 1 patch x 4 rows; grid = 128 patches x 128.
__global__ __launch_bounds__(256) void k_write(
    const float* __restrict__ pre0, const float* __restrict__ gt0,
    const float* __restrict__ pre1, const float* __restrict__ gt1,
    const float* __restrict__ pre2, const float* __restrict__ gt2,
    const float* __restrict__ pre3, const float* __restrict__ gt3,
    const int* __restrict__ mask, float* __restrict__ out)
{
    const int NPIX = 16 * 1024 * 1024;
    const int bid    = blockIdx.x;       // 0..16383
    const int patch  = bid >> 7;         // 0..127
    const int rowblk = bid & 127;        // 0..127
    const int t    = threadIdx.x;
    const int wv   = t >> 6;             // 0..3
    const int lane = t & 63;
    const int row  = rowblk * 4 + wv;    // 0..511 within patch

    const int b  = patch >> 3;
    const int pi = (patch >> 2) & 1;
    const int pj = patch & 3;
    const int m  = mask[patch];          // block-uniform -> scalar select
    const int kh = 512 >> m, kw = 256 >> m;
    const int wdim  = 1024 >> m;
    const int pad_h = (512 - kh) >> 1;
    const int pad_w = (256 - kw) >> 1;
    const float* __restrict__ pre = (m == 0) ? pre0 : (m == 1) ? pre1 : (m == 2) ? pre2 : pre3;
    const float* __restrict__ gt  = (m == 0) ? gt0  : (m == 1) ? gt1  : (m == 2) ? gt2  : gt3;

    float* __restrict__ out_img = out + 1;
    float* __restrict__ lab_img = out + 1 + NPIX;
    const int obase = (b << 20) | ((pi * 512 + row) << 10) | (pj << 8);  // +col

    const int  rr     = row - pad_h;
    const bool row_in = (unsigned)rr < (unsigned)kh;
    const int  ibase  = b * wdim * wdim + (pi * kh + rr) * wdim + pj * kw;  // +cc (valid iff row_in)

    if (lane < 63) {
        const int col0 = 4 * lane + 3;          // 3..251
        const int cc0  = col0 - pad_w;          // ≡3 mod 4 (pad_w ≡ 0 mod 4)
        f32x4 o4, l4;
        if (row_in && cc0 >= 0 && cc0 + 4 <= kw) {
            // interior: cc0 >= 3 (≡3 mod 4), so a0 = cc0-3 >= 0 and aligned
            const int a0 = ibase + cc0 - 3;
            const f32x4 pa = *reinterpret_cast<const f32x4*>(pre + a0);
            const f32x4 pb = *reinterpret_cast<const f32x4*>(pre + a0 + 4);
            const f32x4 ga = *reinterpret_cast<const f32x4*>(gt + a0);
            const f32x4 gb = *reinterpret_cast<const f32x4*>(gt + a0 + 4);
            o4 = (f32x4){pa[3], pb[0], pb[1], pb[2]} * 0.005f;
            l4 = (f32x4){ga[3], gb[0], gb[1], gb[2]};
        } else {
            // pad row, or the <=2 lanes straddling the pad/interior boundary
#pragma unroll
            for (int p = 0; p < 4; ++p) {
                const int cc = cc0 + p;
                float ov = 0.001f, lv = 0.001f;        // 0.2 / WEIGHT
                if (row_in && (unsigned)cc < (unsigned)kw) {
                    ov = pre[ibase + cc] * 0.005f;
                    lv = gt[ibase + cc];
                }
                o4[p] = ov; l4[p] = lv;
            }
        }
        __builtin_nontemporal_store(o4, reinterpret_cast<f32x4*>(out_img + obase + col0));
        __builtin_nontemporal_store(l4, reinterpret_cast<f32x4*>(lab_img + obase + col0));
    } else {
        // leftover cols of this row: {0,1,2,255}
        const int cols[4] = {0, 1, 2, 255};
#pragma unroll
        for (int p = 0; p < 4; ++p) {
            const int col = cols[p];
            const int cc  = col - pad_w;
            float ov = 0.001f, lv = 0.001f;
            if (row_in && (unsigned)cc < (unsigned)kw) {
                ov = pre[ibase + cc] * 0.005f;
                lv = gt[ibase + cc];
            }
            __builtin_nontemporal_store(ov, out_img + obase + col);
            __builtin_nontemporal_store(lv, lab_img + obase + col);
        }
    }
}

extern "C" void kernel_launch(void* const* d_in, const int* in_sizes, int n_in,
                              void* d_out, int out_size, void* d_ws, size_t ws_size,
                              hipStream_t stream) {
    // setup_inputs() dict order is INTERLEAVED: pre0, gt0, pre1, gt1, ...
    const float* pre0 = (const float*)d_in[0];
    const float* gt0  = (const float*)d_in[1];
    const float* pre1 = (const float*)d_in[2];
    const float* gt1  = (const float*)d_in[3];
    const float* pre2 = (const float*)d_in[4];
    const float* gt2  = (const float*)d_in[5];
    const float* pre3 = (const float*)d_in[6];
    const float* gt3  = (const float*)d_in[7];

    float* out = (float*)d_out;             // [0]=loss, [1..]=out_img, then lab_img
    float* pA  = (float*)d_ws;              // 5504 each, SoA planes
    float* pN  = pA + 5504;
    float* pQ  = pA + 11008;
    int*   mask = (int*)(pA + 16512);       // 128 ints

    k_err<<<5504, 256, 0, stream>>>(pre0, gt0, pre1, gt1, pre2, gt2, pre3, gt3, pA, pN, pQ);
    k_finalize<<<1, 256, 0, stream>>>(pA, pN, pQ, mask, out);
    k_write<<<16384, 256, 0, stream>>>(pre0, gt0, pre1, gt1, pre2, gt2, pre3, gt3, mask, out);
}